// Round 5
// baseline (10938.791 us; speedup 1.0000x reference)
//
#include <hip/hip_runtime.h>

typedef unsigned short u16;
typedef unsigned int uint;

using f32x4 = __attribute__((ext_vector_type(4))) float;
using bf16x8 = __attribute__((ext_vector_type(8))) __bf16;

static __device__ __forceinline__ bf16x8 as_bf16x8(uint4 u) {
    union { uint4 a; bf16x8 b; } c; c.a = u; return c.b;
}
static __device__ __forceinline__ float bf2f(u16 h) {
    union { uint u; float f; } c; c.u = ((uint)h) << 16; return c.f;
}
static __device__ __forceinline__ u16 f2bf(float f) {
    union { float f; uint u; } c; c.f = f;
    uint u = c.u;
    return (u16)((u + 0x7fffu + ((u >> 16) & 1u)) >> 16);
}
static __device__ __forceinline__ float fast_sigmoid(float x) {
    x = fminf(30.f, fmaxf(-30.f, x));
    return __builtin_amdgcn_rcpf(1.0f + __builtin_amdgcn_exp2f(x * -1.44269504f));
}
static __device__ __forceinline__ float fast_tanh(float x) {
    x = fminf(15.f, fmaxf(-15.f, x));
    return 1.0f - 2.0f * __builtin_amdgcn_rcpf(1.0f + __builtin_amdgcn_exp2f(x * 2.88539008f));
}

// dtype detector (fp32 vs bf16 buffers) — deterministic, graph-capture safe.
static __device__ __forceinline__ int detect_fp32(const uint* w, int nwords) {
    int hits = 0;
    for (int i = 0; i < nwords; ++i) { uint e = (w[i] >> 7) & 0xffu; hits += (e >= 0x80u); }
    return hits > (nwords >> 3);
}
static __device__ __forceinline__ u16 load_bf(const void* p, int i, int fp32) {
    return fp32 ? f2bf(((const float*)p)[i]) : ((const u16*)p)[i];
}

// device-coherent 16B load / 2B store (bypass non-coherent L1/L2, hit L3 point)
static __device__ __forceinline__ uint4 coh_load16(const u16* src) {
    uint4 v;
    asm volatile("global_load_dwordx4 %0, %1, off sc0 sc1\n\ts_waitcnt vmcnt(0)"
                 : "=v"(v) : "v"(src) : "memory");
    return v;
}
static __device__ __forceinline__ void coh_store2(u16* dst, u16 val) {
    uint v32 = val;
    asm volatile("global_store_short %0, %1, off sc0 sc1" :: "v"(dst), "v"(v32) : "memory");
}

// Fragment-ordered weight pack for N-partitioned blocks:
//   wp[((p*KS + ks)*16 + w)*512 + lane*8 + j]
//   n = p*256 + w*16 + (lane&15) = 4*unit + gate;  k = ks*32 + (lane>>4)*8 + j
// grid: 4*KS blocks x 1024 threads.
__global__ void pack_w(const void* wf, const void* wi, const void* wc, const void* wo,
                       const void* bbf, const void* bbi, const void* bbc, const void* bbo,
                       u16* __restrict__ wp, u16* __restrict__ bp, int K, int KS) {
    __shared__ int sfp;
    if (threadIdx.x == 0) sfp = detect_fp32((const uint*)wf, 256);
    __syncthreads();
    const int fp32 = sfp;
    int p = blockIdx.x / KS, ks = blockIdx.x % KS;
    int tid = threadIdx.x;
    int w = tid >> 6, lane = tid & 63, c16 = lane & 15, q = lane >> 4;
    int n = p * 256 + w * 16 + c16;
    int u = n >> 2, g = n & 3;
    const void* W = (g == 0) ? wf : (g == 1) ? wi : (g == 2) ? wc : wo;
    union { u16 v[8]; uint4 u4; } tmp;
#pragma unroll
    for (int j = 0; j < 8; ++j) {
        int k = ks * 32 + q * 8 + j;
        tmp.v[j] = (k < K) ? load_bf(W, k * 256 + u, fp32) : (u16)0;
    }
    *(uint4*)(wp + ((p * KS + ks) * 16 + w) * 512 + lane * 8) = tmp.u4;
    if (ks == 0 && tid < 256) {
        int n2 = p * 256 + tid;
        int g2 = n2 & 3;
        const void* B = (g2 == 0) ? bbf : (g2 == 1) ? bbi : (g2 == 2) ? bbc : bbo;
        bp[n2] = load_bf(B, n2 >> 2, fp32);
    }
}

__global__ void pack_out(const void* w_out, const void* b_out,
                         u16* __restrict__ wob, u16* __restrict__ bob) {
    __shared__ int sfp;
    if (threadIdx.x == 0) sfp = detect_fp32((const uint*)w_out, 128);
    __syncthreads();
    if (threadIdx.x < 256) wob[threadIdx.x] = load_bf(w_out, threadIdx.x, sfp);
    if (threadIdx.x == 0) bob[0] = load_bf(b_out, 0, sfp);
}

// K-loop: acc += HX[16,K] x W[K, 16 cols of this wave], fragment-ordered weights.
template <int KS, int HXS>
static __device__ __forceinline__ void kloop(const u16* __restrict__ wslab, const u16* hx,
                                             int lane, f32x4& acc) {
    const int c16 = lane & 15, q = lane >> 4;
    const u16* aptr = hx + c16 * HXS + q * 8;
    const u16* bptr = wslab + lane * 8;
    constexpr int NC = KS / 4;
    uint4 A[2][4], B[2][4];
#pragma unroll
    for (int j = 0; j < 4; ++j) {
        B[0][j] = *(const uint4*)(bptr + j * 16 * 512);
        A[0][j] = *(const uint4*)(aptr + j * 32);
    }
#pragma unroll
    for (int c = 0; c < NC; ++c) {
        const int cur = c & 1;
        if (c + 1 < NC) {
#pragma unroll
            for (int j = 0; j < 4; ++j) {
                B[cur ^ 1][j] = *(const uint4*)(bptr + ((c + 1) * 4 + j) * 16 * 512);
                A[cur ^ 1][j] = *(const uint4*)(aptr + ((c + 1) * 4 + j) * 32);
            }
        }
#pragma unroll
        for (int j = 0; j < 4; ++j)
            acc = __builtin_amdgcn_mfma_f32_16x16x32_bf16(as_bf16x8(A[cur][j]), as_bf16x8(B[cur][j]), acc, 0, 0, 0);
    }
}

#define HX1S 392   // 384 K-cols + 8 pad
#define HX2S 520   // 512 K-cols + 8 pad
#define SCRW 20    // 16 cols + 4 pad (8B-aligned rows)

__global__ void __launch_bounds__(1024, 1)
lstm_kernel(const int* __restrict__ tokens, const void* __restrict__ emb,
            const u16* __restrict__ wp1, const u16* __restrict__ b1p,
            const u16* __restrict__ wp2, const u16* __restrict__ b2p,
            const u16* __restrict__ wob, const u16* __restrict__ bob,
            uint* __restrict__ flags, u16* __restrict__ hbuf,
            float* __restrict__ out) {
    __shared__ __align__(16) u16 hx1[16 * HX1S];        // [r][ h1(256) | x(100) | 0 ]
    __shared__ __align__(16) u16 hx2[16 * HX2S];        // [r][ h2(256) | h1(256) ]
    __shared__ __align__(16) u16 scr[16 * 16 * SCRW];   // [wave][row][col] Z scratch
    __shared__ int sfp_emb;

    const int tid = threadIdx.x;
    const int lane = tid & 63;
    const int w = tid >> 6;              // wave 0..15 -> block n-tile w (16 cols)
    const int c16 = lane & 15;
    const int q = lane >> 4;
    const int p = blockIdx.x >> 6;       // N-part 0..3 (units [64p, 64p+64))
    const int grp = blockIdx.x & 63;     // M-group (rows [16*grp, 16*grp+16))
    const int row0 = grp * 16;

    // gate-thread mapping: one (row, local-unit) per thread
    const int r = tid >> 6;              // row 0..15 (== wave)
    const int ul = tid & 63;             // local unit 0..63
    const int U = p * 64 + ul;           // global unit

    if (tid == 0) sfp_emb = detect_fp32((const uint*)emb, 256);
    {
        uint* p1 = (uint*)hx1;
        for (int i = tid; i < 16 * HX1S / 2; i += 1024) p1[i] = 0;
        uint* p2 = (uint*)hx2;
        for (int i = tid; i < 16 * HX2S / 2; i += 1024) p2[i] = 0;
    }
    __syncthreads();
    const int efp = sfp_emb;

    // gather x(t=0)
    if (tid < 512) {
        int rr = tid >> 5, s32 = tid & 31;
        if (s32 < 25) {
            int tok = tokens[(row0 + rr) * 80 + 0];
            ushort4 xv;
            if (efp) {
                float4 f = *(const float4*)((const float*)emb + tok * 100 + s32 * 4);
                xv.x = f2bf(f.x); xv.y = f2bf(f.y); xv.z = f2bf(f.z); xv.w = f2bf(f.w);
            } else {
                xv = *(const ushort4*)((const u16*)emb + tok * 100 + s32 * 4);
            }
            *(ushort4*)(hx1 + rr * HX1S + 256 + s32 * 4) = xv;
        }
    }
    ushort4 bw1 = *(const ushort4*)(b1p + U * 4);
    ushort4 bw2 = *(const ushort4*)(b2p + U * 4);
    const float b1f0 = bf2f(bw1.x), b1f1 = bf2f(bw1.y), b1f2 = bf2f(bw1.z), b1f3 = bf2f(bw1.w);
    const float b2f0 = bf2f(bw2.x), b2f1 = bf2f(bw2.y), b2f2 = bf2f(bw2.z), b2f3 = bf2f(bw2.w);
    float c1s = 0.f, c2s = 0.f;

    const u16* w1slab = wp1 + (p * 12 * 16 + w) * 512;
    const u16* w2slab = wp2 + (p * 16 * 16 + w) * 512;
    u16* swv = scr + w * (16 * SCRW);
    const u16* zrd = scr + (ul >> 2) * (16 * SCRW) + r * SCRW + 4 * (ul & 3);
    uint* flagbase = flags + grp * 176;

    __syncthreads();

#pragma unroll 1
    for (int t = 0; t < 80; ++t) {
        u16* hbL1 = hbuf + ((grp * 2 + 0) * 2 + (t & 1)) * 4096;
        u16* hbL2 = hbuf + ((grp * 2 + 1) * 2 + (t & 1)) * 4096;

        // ---------- Layer 1 GEMM ----------
        f32x4 acc = (f32x4){0.f, 0.f, 0.f, 0.f};
        kloop<12, HX1S>(w1slab, hx1, lane, acc);
#pragma unroll
        for (int j = 0; j < 4; ++j)
            swv[(q * 4 + j) * SCRW + c16] = f2bf(acc[j]);
        __syncthreads();  // B1: Z1 visible to all waves

        // ---------- gates 1 (+ x(t+1) prefetch) ----------
        {
            ushort4 xv;
            int xr = tid >> 5, xs = tid & 31;
            bool xact = (tid < 512) && (xs < 25) && (t < 79);
            if (xact) {
                int tok = tokens[(row0 + xr) * 80 + t + 1];
                if (efp) {
                    float4 f = *(const float4*)((const float*)emb + tok * 100 + xs * 4);
                    xv.x = f2bf(f.x); xv.y = f2bf(f.y); xv.z = f2bf(f.z); xv.w = f2bf(f.w);
                } else {
                    xv = *(const ushort4*)((const u16*)emb + tok * 100 + xs * 4);
                }
            }
            ushort4 zz = *(const ushort4*)zrd;
            float gf = fast_sigmoid(bf2f(zz.x) + b1f0);
            float gi = fast_sigmoid(bf2f(zz.y) + b1f1);
            float gc = fast_tanh(bf2f(zz.z) + b1f2);
            float go = fast_sigmoid(bf2f(zz.w) + b1f3);
            float cn = gf * c1s + gi * gc;
            c1s = cn;
            u16 hb = f2bf(go * fast_tanh(cn));
            hx1[r * HX1S + U] = hb;
            hx2[r * HX2S + 256 + U] = hb;
            coh_store2(hbL1 + p * 1024 + r * 64 + ul, hb);
            if (xact) *(ushort4*)(hx1 + xr * HX1S + 256 + xs * 4) = xv;
        }
        __threadfence();
        __syncthreads();  // B2: chunk stores drained
        if (tid == 0) {
            uint* fp = flagbase + t * 2 + 0;
            __hip_atomic_fetch_add(fp, 1u, __ATOMIC_RELEASE, __HIP_MEMORY_SCOPE_AGENT);
            while (__hip_atomic_load(fp, __ATOMIC_ACQUIRE, __HIP_MEMORY_SCOPE_AGENT) < 4u)
                __builtin_amdgcn_s_sleep(2);
        }
        __syncthreads();  // B3: all 4 chunks of h1(t) published
        if (tid < 384) {
            int fi = tid >> 7, idx = tid & 127;
            int rr = idx >> 3, c8 = idx & 7;
            int pf = fi + (fi >= p);
            uint4 v = coh_load16(hbL1 + pf * 1024 + rr * 64 + c8 * 8);
            *(uint4*)(hx1 + rr * HX1S + pf * 64 + c8 * 8) = v;
            *(uint4*)(hx2 + rr * HX2S + 256 + pf * 64 + c8 * 8) = v;
        }
        __syncthreads();  // B4: full h1(t) in LDS

        // ---------- Layer 2 GEMM ----------
        f32x4 acc2 = (f32x4){0.f, 0.f, 0.f, 0.f};
        kloop<16, HX2S>(w2slab, hx2, lane, acc2);
#pragma unroll
        for (int j = 0; j < 4; ++j)
            swv[(q * 4 + j) * SCRW + c16] = f2bf(acc2[j]);
        __syncthreads();  // B5

        // ---------- gates 2 ----------
        {
            ushort4 zz = *(const ushort4*)zrd;
            float gf = fast_sigmoid(bf2f(zz.x) + b2f0);
            float gi = fast_sigmoid(bf2f(zz.y) + b2f1);
            float gc = fast_tanh(bf2f(zz.z) + b2f2);
            float go = fast_sigmoid(bf2f(zz.w) + b2f3);
            float cn = gf * c2s + gi * gc;
            c2s = cn;
            u16 hb = f2bf(go * fast_tanh(cn));
            hx2[r * HX2S + U] = hb;
            coh_store2(hbL2 + p * 1024 + r * 64 + ul, hb);
        }
        __threadfence();
        __syncthreads();  // B6
        if (tid == 0) {
            uint* fp = flagbase + t * 2 + 1;
            __hip_atomic_fetch_add(fp, 1u, __ATOMIC_RELEASE, __HIP_MEMORY_SCOPE_AGENT);
            while (__hip_atomic_load(fp, __ATOMIC_ACQUIRE, __HIP_MEMORY_SCOPE_AGENT) < 4u)
                __builtin_amdgcn_s_sleep(2);
        }
        __syncthreads();  // B7: all 4 chunks of h2(t) published
        if (tid < 384) {
            int fi = tid >> 7, idx = tid & 127;
            int rr = idx >> 3, c8 = idx & 7;
            int pf = fi + (fi >= p);
            uint4 v = coh_load16(hbL2 + pf * 1024 + rr * 64 + c8 * 8);
            *(uint4*)(hx2 + rr * HX2S + pf * 64 + c8 * 8) = v;
        }
        // next-iter B1..B4 order these writes before any hx2 read.
    }
    __syncthreads();

    // ---------- output: sigmoid(h2 @ w_out + b_out) — p==0 blocks only ----------
    if (p == 0) {
        if (tid < 512) {
            int rr = tid >> 5, s = tid & 31;
            uint4 hv = *(const uint4*)(hx2 + rr * HX2S + s * 8);
            uint4 wv = *(const uint4*)(wob + s * 8);
            const u16* hp = (const u16*)&hv;
            const u16* wp = (const u16*)&wv;
            float dot = 0.f;
#pragma unroll
            for (int i = 0; i < 8; ++i) dot += bf2f(hp[i]) * bf2f(wp[i]);
            float* psum = (float*)scr;
            psum[rr * 32 + s] = dot;
        }
        __syncthreads();
        if (tid < 16) {
            float* psum = (float*)scr;
            float ssum = 0.f;
            for (int i = 0; i < 32; ++i) ssum += psum[tid * 32 + i];
            out[row0 + tid] = fast_sigmoid(ssum + bf2f(bob[0]));
        }
    }
}

extern "C" void kernel_launch(void* const* d_in, const int* in_sizes, int n_in,
                              void* d_out, int out_size, void* d_ws, size_t ws_size,
                              hipStream_t stream) {
    const int* tokens = (const int*)d_in[0];
    const void* emb = d_in[1];
    const void* wf1 = d_in[2];  const void* bf1_ = d_in[3];
    const void* wi1 = d_in[4];  const void* bi1_ = d_in[5];
    const void* wc1 = d_in[6];  const void* bc1_ = d_in[7];
    const void* wo1 = d_in[8];  const void* bo1_ = d_in[9];
    const void* wf2 = d_in[10]; const void* bf2_ = d_in[11];
    const void* wi2 = d_in[12]; const void* bi2_ = d_in[13];
    const void* wc2 = d_in[14]; const void* bc2_ = d_in[15];
    const void* wo2 = d_in[16]; const void* bo2_ = d_in[17];
    const void* w_out = d_in[18];
    const void* b_out = d_in[19];

    u16* wp1 = (u16*)d_ws;                 // 4*12*16*512 = 393216 u16
    u16* wp2 = wp1 + 4 * 12 * 16 * 512;    // 4*16*16*512 = 524288 u16
    u16* b1p = wp2 + 4 * 16 * 16 * 512;    // 1024
    u16* b2p = b1p + 1024;                 // 1024
    u16* wob = b2p + 1024;                 // 256
    u16* bob = wob + 256;                  // 8 (pad to keep 16B align)
    uint* flags = (uint*)(bob + 8);        // 64*176 u32 = 45056 B
    u16* hbuf = (u16*)(flags + 64 * 176);  // 64*2*2*4096 u16 = 2 MB

    hipMemsetAsync(flags, 0, 64 * 176 * sizeof(uint), stream);
    pack_w<<<dim3(4 * 12), dim3(1024), 0, stream>>>(wf1, wi1, wc1, wo1, bf1_, bi1_, bc1_, bo1_,
                                                    wp1, b1p, 356, 12);
    pack_w<<<dim3(4 * 16), dim3(1024), 0, stream>>>(wf2, wi2, wc2, wo2, bf2_, bi2_, bc2_, bo2_,
                                                    wp2, b2p, 512, 16);
    pack_out<<<dim3(1), dim3(256), 0, stream>>>(w_out, b_out, wob, bob);
    lstm_kernel<<<dim3(256), dim3(1024), 0, stream>>>(tokens, emb, wp1, b1p, wp2, b2p,
                                                      wob, bob, flags, hbuf, (float*)d_out);
}

// Round 6
// 3775.229 us; speedup vs baseline: 2.8975x; 2.8975x over previous
//
#include <hip/hip_runtime.h>

typedef unsigned short u16;
typedef unsigned int uint;

using f32x4 = __attribute__((ext_vector_type(4))) float;
using bf16x8 = __attribute__((ext_vector_type(8))) __bf16;

static __device__ __forceinline__ bf16x8 as_bf16x8(uint4 u) {
    union { uint4 a; bf16x8 b; } c; c.a = u; return c.b;
}
static __device__ __forceinline__ float bf2f(u16 h) {
    union { uint u; float f; } c; c.u = ((uint)h) << 16; return c.f;
}
static __device__ __forceinline__ u16 f2bf(float f) {
    union { float f; uint u; } c; c.f = f;
    uint u = c.u;
    return (u16)((u + 0x7fffu + ((u >> 16) & 1u)) >> 16);
}
static __device__ __forceinline__ float fast_sigmoid(float x) {
    x = fminf(30.f, fmaxf(-30.f, x));
    return __builtin_amdgcn_rcpf(1.0f + __builtin_amdgcn_exp2f(x * -1.44269504f));
}
static __device__ __forceinline__ float fast_tanh(float x) {
    x = fminf(15.f, fmaxf(-15.f, x));
    return 1.0f - 2.0f * __builtin_amdgcn_rcpf(1.0f + __builtin_amdgcn_exp2f(x * 2.88539008f));
}

// dtype detector (fp32 vs bf16 buffers) — deterministic, graph-capture safe.
static __device__ __forceinline__ int detect_fp32(const uint* w, int nwords) {
    int hits = 0;
    for (int i = 0; i < nwords; ++i) { uint e = (w[i] >> 7) & 0xffu; hits += (e >= 0x80u); }
    return hits > (nwords >> 3);
}
static __device__ __forceinline__ u16 load_bf(const void* p, int i, int fp32) {
    return fp32 ? f2bf(((const float*)p)[i]) : ((const u16*)p)[i];
}

// Fragment-ordered weight pack (round-4 layout):
//   wp[((w*KSTEPS + ks)*4 + nt)*512 + lane*8 + j]
//   n = w*64 + nt*16 + (lane&15) = 4*unit + gate;  k = ks*32 + (lane>>4)*8 + j
__global__ void pack_w(const void* wf, const void* wi, const void* wc, const void* wo,
                       const void* bbf, const void* bbi, const void* bbc, const void* bbo,
                       u16* __restrict__ wp, u16* __restrict__ bp, int K, int KSTEPS) {
    __shared__ int sfp;
    if (threadIdx.x == 0) sfp = detect_fp32((const uint*)wf, 256);
    __syncthreads();
    const int fp32 = sfp;
    int w = blockIdx.x / KSTEPS, ks = blockIdx.x % KSTEPS;
    int nt = threadIdx.x >> 6, lane = threadIdx.x & 63;
    int c16 = lane & 15, q = lane >> 4;
    int n = w * 64 + nt * 16 + c16;
    int u = n >> 2, g = n & 3;
    const void* W = (g == 0) ? wf : (g == 1) ? wi : (g == 2) ? wc : wo;
    union { u16 v[8]; uint4 u4; } tmp;
#pragma unroll
    for (int j = 0; j < 8; ++j) {
        int k = ks * 32 + q * 8 + j;
        tmp.v[j] = (k < K) ? load_bf(W, k * 256 + u, fp32) : (u16)0;
    }
    *(uint4*)(wp + ((w * KSTEPS + ks) * 4 + nt) * 512 + lane * 8) = tmp.u4;
    if (ks == 0 && threadIdx.x < 64) {
        int n2 = w * 64 + threadIdx.x;
        int g2 = n2 & 3;
        const void* B = (g2 == 0) ? bbf : (g2 == 1) ? bbi : (g2 == 2) ? bbc : bbo;
        bp[n2] = load_bf(B, n2 >> 2, fp32);
    }
}

__global__ void pack_out(const void* w_out, const void* b_out,
                         u16* __restrict__ wob, u16* __restrict__ bob) {
    __shared__ int sfp;
    if (threadIdx.x == 0) sfp = detect_fp32((const uint*)w_out, 128);
    __syncthreads();
    if (threadIdx.x < 256) wob[threadIdx.x] = load_bf(w_out, threadIdx.x, sfp);
    if (threadIdx.x == 0) bob[0] = load_bf(b_out, 0, sfp);
}

// Pre-gather x embeddings into dense per-block layout: xd[((grp*80+t)*16+r)*100 + e]
// Removes the random 2MB emb-table walk from the main kernel's L2 (weight residency).
__global__ void pregather_x(const int* __restrict__ tokens, const void* __restrict__ emb,
                            u16* __restrict__ xd) {
    __shared__ int sfp;
    if (threadIdx.x == 0) sfp = detect_fp32((const uint*)emb, 256);
    __syncthreads();
    const int efp = sfp;
    const int grp = blockIdx.x;
    const int r = threadIdx.x >> 5, s = threadIdx.x & 31;
    if (s >= 25) return;
    for (int t = 0; t < 80; ++t) {
        int tok = tokens[(grp * 16 + r) * 80 + t];
        ushort4 xv;
        if (efp) {
            float4 f = *(const float4*)((const float*)emb + tok * 100 + s * 4);
            xv.x = f2bf(f.x); xv.y = f2bf(f.y); xv.z = f2bf(f.z); xv.w = f2bf(f.w);
        } else {
            xv = *(const ushort4*)((const u16*)emb + tok * 100 + s * 4);
        }
        *(ushort4*)(xd + ((grp * 80 + t) * 16 + r) * 100 + s * 4) = xv;
    }
}

// K-loop: acc[nt] += HX[16,K] x W[K, 16 cols], fragment-ordered weights,
// B prefetched 2 chunks ahead (depth-3 rotation) to double loads in flight.
template <int KSTEPS, int HXS>
static __device__ __forceinline__ void kloop(const u16* __restrict__ wslab, const u16* hx,
                                             int lane, f32x4 acc[4]) {
    int c16 = lane & 15, q = lane >> 4;
    const u16* aptr = hx + c16 * HXS + q * 8;
    const u16* bptr = wslab + lane * 8;
    uint4 bb[3][4];
#pragma unroll
    for (int nt = 0; nt < 4; ++nt) {
        bb[0][nt] = *(const uint4*)(bptr + nt * 512);
        bb[1][nt] = *(const uint4*)(bptr + (4 + nt) * 512);
    }
#pragma unroll
    for (int ks = 0; ks < KSTEPS; ++ks) {
        const int cur = ks % 3;
        if (ks + 2 < KSTEPS) {
            const int nxt = (ks + 2) % 3;
#pragma unroll
            for (int nt = 0; nt < 4; ++nt)
                bb[nxt][nt] = *(const uint4*)(bptr + ((ks + 2) * 4 + nt) * 512);
        }
        bf16x8 a = as_bf16x8(*(const uint4*)(aptr + ks * 32));
#pragma unroll
        for (int nt = 0; nt < 4; ++nt)
            acc[nt] = __builtin_amdgcn_mfma_f32_16x16x32_bf16(a, as_bf16x8(bb[cur][nt]), acc[nt], 0, 0, 0);
    }
}

#define HX1S 392   // 384 K-cols + 8 pad
#define HX2S 520   // 512 K-cols + 8 pad
#define SCRS 68    // 64 gate-cols + 4 pad

__global__ void __launch_bounds__(1024, 1)
lstm_kernel(const u16* __restrict__ xd,
            const u16* __restrict__ wp1, const u16* __restrict__ b1p,
            const u16* __restrict__ wp2, const u16* __restrict__ b2p,
            const u16* __restrict__ wob, const u16* __restrict__ bob,
            float* __restrict__ out) {
    __shared__ __align__(16) u16 hx1[16 * HX1S];        // [r][ h1(256) | x(100) | 0 ]
    __shared__ __align__(16) u16 hx2[16 * HX2S];        // [r][ h2(256) | h1(256) ]
    __shared__ __align__(16) u16 scr[16 * 16 * SCRS];   // per-wave Z scratch

    const int tid = threadIdx.x;
    const int lane = tid & 63;
    const int w = tid >> 6;          // wave 0..15 -> gate-cols [64w, 64w+64)
    const int c16 = lane & 15;
    const int q = lane >> 4;
    const int grp = blockIdx.x;
    const int row0 = grp * 16;

    const int ul = lane & 15;        // unit-local for gates
    const int U = w * 16 + ul;       // global unit 0..255

    {
        uint* p1 = (uint*)hx1;
        for (int i = tid; i < 16 * HX1S / 2; i += 1024) p1[i] = 0;
        uint* p2 = (uint*)hx2;
        for (int i = tid; i < 16 * HX2S / 2; i += 1024) p2[i] = 0;
    }
    float c1s[4], c2s[4];
#pragma unroll
    for (int j = 0; j < 4; ++j) { c1s[j] = 0.f; c2s[j] = 0.f; }

    // x(t=0) from dense buffer
    const int xr = tid >> 5, xs = tid & 31;
    const bool xth = (tid < 512) && (xs < 25);
    if (xth) {
        ushort4 v = *(const ushort4*)(xd + ((grp * 80 + 0) * 16 + xr) * 100 + xs * 4);
        *(ushort4*)(hx1 + xr * HX1S + 256 + xs * 4) = v;
    }
    ushort4 bw1 = *(const ushort4*)(b1p + U * 4);
    ushort4 bw2 = *(const ushort4*)(b2p + U * 4);
    const float b1f0 = bf2f(bw1.x), b1f1 = bf2f(bw1.y), b1f2 = bf2f(bw1.z), b1f3 = bf2f(bw1.w);
    const float b2f0 = bf2f(bw2.x), b2f1 = bf2f(bw2.y), b2f2 = bf2f(bw2.z), b2f3 = bf2f(bw2.w);

    __syncthreads();

    u16* sw = scr + w * 16 * SCRS;
    const u16* w1slab = wp1 + w * (12 * 4 * 512);
    const u16* w2slab = wp2 + w * (16 * 4 * 512);

#pragma unroll 1
    for (int t = 0; t < 80; ++t) {
        // x(t+1) load issued early — long latency window over the L1 GEMM
        ushort4 xv;
        bool xact = xth && (t < 79);
        if (xact) xv = *(const ushort4*)(xd + ((grp * 80 + t + 1) * 16 + xr) * 100 + xs * 4);

        // ---------- Layer 1 GEMM ----------
        f32x4 acc[4];
#pragma unroll
        for (int nt = 0; nt < 4; ++nt) acc[nt] = (f32x4){0.f, 0.f, 0.f, 0.f};
        kloop<12, HX1S>(w1slab, hx1, lane, acc);
#pragma unroll
        for (int nt = 0; nt < 4; ++nt)
#pragma unroll
            for (int j = 0; j < 4; ++j)
                sw[(q * 4 + j) * SCRS + nt * 16 + c16] = f2bf(acc[nt][j]);
        __syncthreads();  // B1

        // ---------- gates 1 ----------
#pragma unroll
        for (int j = 0; j < 4; ++j) {
            int r = q * 4 + j;
            ushort4 zz = *(const ushort4*)(sw + r * SCRS + ul * 4);
            float gf = fast_sigmoid(bf2f(zz.x) + b1f0);
            float gi = fast_sigmoid(bf2f(zz.y) + b1f1);
            float gc = fast_tanh(bf2f(zz.z) + b1f2);
            float go = fast_sigmoid(bf2f(zz.w) + b1f3);
            float cn = gf * c1s[j] + gi * gc;
            c1s[j] = cn;
            u16 hb = f2bf(go * fast_tanh(cn));
            hx1[r * HX1S + U] = hb;
            hx2[r * HX2S + 256 + U] = hb;
        }
        if (xact) *(ushort4*)(hx1 + xr * HX1S + 256 + xs * 4) = xv;
        __syncthreads();  // B2

        // ---------- Layer 2 GEMM ----------
        f32x4 acc2[4];
#pragma unroll
        for (int nt = 0; nt < 4; ++nt) acc2[nt] = (f32x4){0.f, 0.f, 0.f, 0.f};
        kloop<16, HX2S>(w2slab, hx2, lane, acc2);
#pragma unroll
        for (int nt = 0; nt < 4; ++nt)
#pragma unroll
            for (int j = 0; j < 4; ++j)
                sw[(q * 4 + j) * SCRS + nt * 16 + c16] = f2bf(acc2[nt][j]);
        __syncthreads();  // B3

        // ---------- gates 2 ----------
#pragma unroll
        for (int j = 0; j < 4; ++j) {
            int r = q * 4 + j;
            ushort4 zz = *(const ushort4*)(sw + r * SCRS + ul * 4);
            float gf = fast_sigmoid(bf2f(zz.x) + b2f0);
            float gi = fast_sigmoid(bf2f(zz.y) + b2f1);
            float gc = fast_tanh(bf2f(zz.z) + b2f2);
            float go = fast_sigmoid(bf2f(zz.w) + b2f3);
            float cn = gf * c2s[j] + gi * gc;
            c2s[j] = cn;
            hx2[r * HX2S + U] = f2bf(go * fast_tanh(cn));
        }
        // scr is wave-private; hx hazards ordered by B1/B2 of next iteration.
    }
    __syncthreads();

    // ---------- output: sigmoid(h2 @ w_out + b_out), fp32 store ----------
    if (tid < 512) {
        int rr = tid >> 5, s = tid & 31;
        uint4 hv = *(const uint4*)(hx2 + rr * HX2S + s * 8);
        uint4 wv = *(const uint4*)(wob + s * 8);
        const u16* hp = (const u16*)&hv;
        const u16* wp = (const u16*)&wv;
        float dot = 0.f;
#pragma unroll
        for (int i = 0; i < 8; ++i) dot += bf2f(hp[i]) * bf2f(wp[i]);
        float* psum = (float*)scr;
        psum[rr * 32 + s] = dot;
    }
    __syncthreads();
    if (tid < 16) {
        float* psum = (float*)scr;
        float ssum = 0.f;
        for (int i = 0; i < 32; ++i) ssum += psum[tid * 32 + i];
        out[row0 + tid] = fast_sigmoid(ssum + bf2f(bob[0]));
    }
}

extern "C" void kernel_launch(void* const* d_in, const int* in_sizes, int n_in,
                              void* d_out, int out_size, void* d_ws, size_t ws_size,
                              hipStream_t stream) {
    const int* tokens = (const int*)d_in[0];
    const void* emb = d_in[1];
    const void* wf1 = d_in[2];  const void* bf1_ = d_in[3];
    const void* wi1 = d_in[4];  const void* bi1_ = d_in[5];
    const void* wc1 = d_in[6];  const void* bc1_ = d_in[7];
    const void* wo1 = d_in[8];  const void* bo1_ = d_in[9];
    const void* wf2 = d_in[10]; const void* bf2_ = d_in[11];
    const void* wi2 = d_in[12]; const void* bi2_ = d_in[13];
    const void* wc2 = d_in[14]; const void* bc2_ = d_in[15];
    const void* wo2 = d_in[16]; const void* bo2_ = d_in[17];
    const void* w_out = d_in[18];
    const void* b_out = d_in[19];

    u16* wp1 = (u16*)d_ws;                 // 16*12*4*512 = 393216 u16
    u16* wp2 = wp1 + 16 * 12 * 4 * 512;    // 16*16*4*512 = 524288 u16
    u16* b1p = wp2 + 16 * 16 * 4 * 512;    // 1024
    u16* b2p = b1p + 1024;                 // 1024
    u16* wob = b2p + 1024;                 // 256
    u16* bob = wob + 256;                  // 8 (pad, keeps 16B align)
    u16* xd  = bob + 8;                    // 64*80*16*100 = 8,192,000 u16 (~16.4 MB)

    pack_w<<<dim3(16 * 12), dim3(256), 0, stream>>>(wf1, wi1, wc1, wo1, bf1_, bi1_, bc1_, bo1_,
                                                    wp1, b1p, 356, 12);
    pack_w<<<dim3(16 * 16), dim3(256), 0, stream>>>(wf2, wi2, wc2, wo2, bf2_, bi2_, bc2_, bo2_,
                                                    wp2, b2p, 512, 16);
    pack_out<<<dim3(1), dim3(256), 0, stream>>>(w_out, b_out, wob, bob);
    pregather_x<<<dim3(64), dim3(512), 0, stream>>>(tokens, emb, xd);
    lstm_kernel<<<dim3(64), dim3(1024), 0, stream>>>(xd, wp1, b1p, wp2, b2p,
                                                     wob, bob, (float*)d_out);
}